// Round 1
// baseline (113.330 us; speedup 1.0000x reference)
//
#include <hip/hip_runtime.h>
#include <stdint.h>

typedef __bf16 bf16x8 __attribute__((ext_vector_type(8)));
typedef float  f32x4  __attribute__((ext_vector_type(4)));

// ArcFace constants (margin=0.5, scale=70)
constexpr float COS_M = 0.8775825618903728f;
constexpr float SIN_M = 0.4794255386042030f;
constexpr float MM    = 0.2397127693021015f;   // sin(pi-0.5)*0.5
constexpr float SCALE = 70.0f;
constexpr float LOG2E = 1.4426950408889634f;
constexpr float CA =  SCALE * COS_M * LOG2E;   // coeff on cos
constexpr float CB =  SCALE * SIN_M * LOG2E;   // coeff on sin
constexpr float CC = -SCALE * LOG2E;           // -70 shift, log2 domain

constexpr int NB = 2048, NC = 100000, ND = 128;
constexpr int BR = 128, BC = 160, TPG = 5;     // grid = 16 row-blocks x 125 class-groups

__device__ __forceinline__ unsigned short f2bf(float f) {
  union { float f; uint32_t u; } x; x.f = f;
  uint32_t u = x.u;
  return (unsigned short)((u + 0x7fffu + ((u >> 16) & 1u)) >> 16);  // RNE
}
__device__ __forceinline__ float bf2f(uint32_t bits16) {
  union { uint32_t u; float f; } x; x.u = bits16 << 16;
  return x.f;
}

// ---- normalize x rows -> bf16 (linear layout); also zero rowsum ----
__global__ void __launch_bounds__(256) k_norm_x(const float* __restrict__ x,
                                                uint32_t* __restrict__ xn,
                                                float* __restrict__ rowsum) {
  const int wv = threadIdx.x >> 6, lane = threadIdx.x & 63;
  if (blockIdx.x < 8) rowsum[blockIdx.x * 256 + threadIdx.x] = 0.0f;
  const int row = blockIdx.x * 4 + wv;                  // 512 blocks
  const float2 v = reinterpret_cast<const float2*>(x + row * ND)[lane];
  float ss = v.x * v.x + v.y * v.y;
  #pragma unroll
  for (int off = 1; off < 64; off <<= 1) ss += __shfl_xor(ss, off, 64);
  const float sc = __builtin_amdgcn_rsqf(fmaxf(ss, 1e-24f));
  const uint32_t p = (uint32_t)f2bf(v.x * sc) | ((uint32_t)f2bf(v.y * sc) << 16);
  xn[row * 64 + lane] = p;
}

// ---- normalize weight rows -> bf16, stored XOR-swizzled (byte ^= (c&7)<<4) ----
__global__ void __launch_bounds__(256) k_norm_w(const float* __restrict__ w,
                                                uint32_t* __restrict__ wn) {
  const int wv = threadIdx.x >> 6, lane = threadIdx.x & 63;
  const int c = blockIdx.x * 4 + wv;                    // 25000 blocks
  const float2 v = reinterpret_cast<const float2*>(w + c * ND)[lane];
  float ss = v.x * v.x + v.y * v.y;
  #pragma unroll
  for (int off = 1; off < 64; off <<= 1) ss += __shfl_xor(ss, off, 64);
  const float sc = __builtin_amdgcn_rsqf(fmaxf(ss, 1e-24f));
  const uint32_t p = (uint32_t)f2bf(v.x * sc) | ((uint32_t)f2bf(v.y * sc) << 16);
  const uint32_t byte = ((uint32_t)(4 * lane)) ^ (((uint32_t)c & 7u) << 4);
  wn[c * 64 + (byte >> 2)] = p;
}

// ---- target-column cosine (for one-hot correction) ----
__global__ void __launch_bounds__(256) k_tdot(const uint32_t* __restrict__ xn,
                                              const uint32_t* __restrict__ wn,
                                              const int* __restrict__ tgt,
                                              float* __restrict__ cost) {
  const int wv = threadIdx.x >> 6, lane = threadIdx.x & 63;
  const int b = blockIdx.x * 4 + wv;                    // 512 blocks
  const int t = tgt[b];
  const uint32_t xa = xn[b * 64 + lane];
  const uint32_t bo = ((uint32_t)(4 * lane)) ^ (((uint32_t)t & 7u) << 4);
  const uint32_t wa = wn[t * 64 + (bo >> 2)];
  float d = bf2f(xa & 0xffffu) * bf2f(wa & 0xffffu) + bf2f(xa >> 16) * bf2f(wa >> 16);
  #pragma unroll
  for (int off = 1; off < 64; off <<= 1) d += __shfl_xor(d, off, 64);
  if (lane == 0) cost[b] = d;
}

// ---- main fused GEMM + margin-transform + exp accumulate ----
// grid = 16 * 125 = 2000 blocks, 256 threads (4 waves, 32 rows each)
__global__ void __launch_bounds__(256, 2) k_main(const uint32_t* __restrict__ xn,
                                                 const uint32_t* __restrict__ wn,
                                                 float* __restrict__ rowsum) {
  __shared__ uint32_t lds[2][BC * 64];                  // 2 x 40 KB
  const int wv = threadIdx.x >> 6, lane = threadIdx.x & 63;
  const int rb = blockIdx.x & 15;                       // row block
  const int cg = blockIdx.x >> 4;                       // class group (125)
  const int rowbase = rb * BR + wv * 32;

  // A fragments: full K=128 in registers (layout: row=lane&15, k=8*(lane>>4)+e)
  bf16x8 afrag[2][4];
  #pragma unroll
  for (int m = 0; m < 2; ++m)
    #pragma unroll
    for (int kk = 0; kk < 4; ++kk) {
      const int row = rowbase + 16 * m + (lane & 15);
      afrag[m][kk] = *reinterpret_cast<const bf16x8*>(xn + row * 64 + 16 * kk + 4 * (lane >> 4));
    }

  auto stage = [&](int tile, int buf) {
    const int cbase = cg * (BC * TPG) + tile * BC;
    const uint32_t* src = wn + cbase * 64 + wv * 2560 + lane * 4;   // 10KB per wave
    uint32_t* dst = &lds[buf][wv * 2560 + lane * 4];
    #pragma unroll
    for (int i = 0; i < 10; ++i) {
      __builtin_amdgcn_global_load_lds(
          (const __attribute__((address_space(1))) uint32_t*)(const void*)(src + i * 256),
          (__attribute__((address_space(3))) uint32_t*)(void*)(dst + i * 256),
          16, 0, 0);
    }
  };

  float rsum[2][4] = {{0.f,0.f,0.f,0.f},{0.f,0.f,0.f,0.f}};

  stage(0, 0);
  __syncthreads();

  for (int t = 0; t < TPG; ++t) {
    const int cur = t & 1;
    if (t + 1 < TPG) stage(t + 1, cur ^ 1);
    const uint32_t* lb = lds[cur];
    f32x4 acc[2][10] = {};
    #pragma unroll
    for (int kk = 0; kk < 4; ++kk) {
      bf16x8 bfrag[10];
      #pragma unroll
      for (int n = 0; n < 10; ++n) {
        const uint32_t r = 16u * n + (lane & 15);
        const uint32_t byteoff = r * 256u +
            (((uint32_t)(64 * kk + 16 * (lane >> 4))) ^ ((r & 7u) << 4));
        bfrag[n] = *reinterpret_cast<const bf16x8*>(lb + (byteoff >> 2));
      }
      #pragma unroll
      for (int m = 0; m < 2; ++m)
        #pragma unroll
        for (int n = 0; n < 10; ++n)
          acc[m][n] = __builtin_amdgcn_mfma_f32_16x16x32_bf16(afrag[m][kk], bfrag[n], acc[m][n], 0, 0, 0);
    }
    // epilogue: exp2(c*CA - sqrt(1-c^2)*CB + CC), accumulate per (m, reg)
    #pragma unroll
    for (int m = 0; m < 2; ++m)
      #pragma unroll
      for (int n = 0; n < 10; ++n)
        #pragma unroll
        for (int e = 0; e < 4; ++e) {
          const float c = acc[m][n][e];
          const float s2 = fmaxf(fmaf(-c, c, 1.0f), 0.0f);
          const float sn = __builtin_amdgcn_sqrtf(s2);
          float tt = fmaf(c, CA, CC);
          tt = fmaf(sn, -CB, tt);
          rsum[m][e] += __builtin_amdgcn_exp2f(tt);
        }
    __syncthreads();   // drains vmcnt -> next tile staged; readers done before overwrite
  }

  // reduce over the 16 column-lanes, then one atomic per row
  #pragma unroll
  for (int m = 0; m < 2; ++m)
    #pragma unroll
    for (int e = 0; e < 4; ++e) {
      float v = rsum[m][e];
      #pragma unroll
      for (int off = 1; off < 16; off <<= 1) v += __shfl_xor(v, off, 64);
      if ((lane & 15) == 0)
        atomicAdd(&rowsum[rowbase + 16 * m + 4 * (lane >> 4) + e], v);
    }
}

// ---- finalize: target-term swap, log, mean ----
__global__ void __launch_bounds__(256) k_final(const float* __restrict__ rowsum,
                                               const float* __restrict__ cost,
                                               float* __restrict__ out) {
  __shared__ float red[256];
  float part = 0.f;
  for (int b = threadIdx.x; b < NB; b += 256) {
    const float ct = cost[b];
    const float s2 = fmaxf(fmaf(-ct, ct, 1.0f), 0.0f);
    const float sn = __builtin_amdgcn_sqrtf(s2);
    float tt = fmaf(ct, CA, CC);
    tt = fmaf(sn, -CB, tt);
    const float v_ctm = __builtin_amdgcn_exp2f(tt);           // term main kernel added
    const float logit_t = SCALE * (ct - MM);                  // true target logit
    const float v_tgt = __builtin_amdgcn_exp2f((logit_t - SCALE) * LOG2E);
    float sum = rowsum[b] - v_ctm + v_tgt;
    sum = fmaxf(sum, 1e-37f);
    part += __builtin_amdgcn_logf(sum) * 0.6931471805599453f + SCALE - logit_t;
  }
  red[threadIdx.x] = part;
  __syncthreads();
  #pragma unroll
  for (int s = 128; s > 0; s >>= 1) {
    if (threadIdx.x < s) red[threadIdx.x] += red[threadIdx.x + s];
    __syncthreads();
  }
  if (threadIdx.x == 0) out[0] = red[0] * (1.0f / NB);
}

extern "C" void kernel_launch(void* const* d_in, const int* in_sizes, int n_in,
                              void* d_out, int out_size, void* d_ws, size_t ws_size,
                              hipStream_t stream) {
  const float* x   = (const float*)d_in[0];
  const int*   tgt = (const int*)d_in[1];
  const float* w   = (const float*)d_in[2];
  float* out = (float*)d_out;

  char* ws = (char*)d_ws;
  const size_t WN_B = (size_t)NC * 256;        // 25,600,000
  const size_t XN_B = (size_t)NB * 256;        // 524,288
  uint32_t* wn     = (uint32_t*)ws;
  uint32_t* xn     = (uint32_t*)(ws + WN_B);
  float*    cost   = (float*)(ws + WN_B + XN_B);
  float*    rowsum = (float*)(ws + WN_B + XN_B + NB * 4);
  if (ws_size < WN_B + XN_B + (size_t)NB * 8) return;

  k_norm_x<<<512,   256, 0, stream>>>(x, xn, rowsum);
  k_norm_w<<<25000, 256, 0, stream>>>(w, wn);
  k_tdot <<<512,   256, 0, stream>>>(xn, wn, tgt, cost);
  k_main <<<2000,  256, 0, stream>>>(xn, wn, rowsum);
  k_final<<<1,     256, 0, stream>>>(rowsum, cost, out);
}

// Round 3
// 109.659 us; speedup vs baseline: 1.0335x; 1.0335x over previous
//
#include <hip/hip_runtime.h>
#include <stdint.h>

typedef __bf16 bf16x8 __attribute__((ext_vector_type(8)));
typedef float  f32x4  __attribute__((ext_vector_type(4)));

// ArcFace constants (margin=0.5, scale=70)
constexpr float COS_M = 0.8775825618903728f;
constexpr float SIN_M = 0.4794255386042030f;
constexpr float MM    = 0.2397127693021015f;   // sin(pi-0.5)*0.5
constexpr float SCALE = 70.0f;
constexpr float LOG2E = 1.4426950408889634f;
constexpr float CA =  SCALE * COS_M * LOG2E;   // coeff on cos
constexpr float CB =  SCALE * SIN_M * LOG2E;   // coeff on sin
constexpr float CC = -SCALE * LOG2E;           // -70 shift, log2 domain

constexpr int NB = 2048, NC = 100000, ND = 128;
constexpr int BR = 128, BC = 80, TPG = 10;     // grid = 16 row-blocks x 125 class-groups

__device__ __forceinline__ unsigned short f2bf(float f) {
  union { float f; uint32_t u; } x; x.f = f;
  uint32_t u = x.u;
  return (unsigned short)((u + 0x7fffu + ((u >> 16) & 1u)) >> 16);  // RNE
}
__device__ __forceinline__ float bf2f(uint32_t bits16) {
  union { uint32_t u; float f; } x; x.u = bits16 << 16;
  return x.f;
}

// ---- normalize x rows -> bf16 (linear layout); also zero rowsum ----
__global__ void __launch_bounds__(256) k_norm_x(const float* __restrict__ x,
                                                uint32_t* __restrict__ xn,
                                                float* __restrict__ rowsum) {
  const int wv = threadIdx.x >> 6, lane = threadIdx.x & 63;
  if (blockIdx.x < 8) rowsum[blockIdx.x * 256 + threadIdx.x] = 0.0f;
  const int row = blockIdx.x * 4 + wv;                  // 512 blocks
  const float2 v = reinterpret_cast<const float2*>(x + row * ND)[lane];
  float ss = v.x * v.x + v.y * v.y;
  #pragma unroll
  for (int off = 1; off < 64; off <<= 1) ss += __shfl_xor(ss, off, 64);
  const float sc = __builtin_amdgcn_rsqf(fmaxf(ss, 1e-24f));
  const uint32_t p = (uint32_t)f2bf(v.x * sc) | ((uint32_t)f2bf(v.y * sc) << 16);
  xn[row * 64 + lane] = p;
}

// ---- normalize weight rows -> bf16, stored XOR-swizzled (byte ^= (c&7)<<4) ----
__global__ void __launch_bounds__(256) k_norm_w(const float* __restrict__ w,
                                                uint32_t* __restrict__ wn) {
  const int wv = threadIdx.x >> 6, lane = threadIdx.x & 63;
  const int c = blockIdx.x * 4 + wv;                    // 25000 blocks
  const float2 v = reinterpret_cast<const float2*>(w + c * ND)[lane];
  float ss = v.x * v.x + v.y * v.y;
  #pragma unroll
  for (int off = 1; off < 64; off <<= 1) ss += __shfl_xor(ss, off, 64);
  const float sc = __builtin_amdgcn_rsqf(fmaxf(ss, 1e-24f));
  const uint32_t p = (uint32_t)f2bf(v.x * sc) | ((uint32_t)f2bf(v.y * sc) << 16);
  const uint32_t byte = ((uint32_t)(4 * lane)) ^ (((uint32_t)c & 7u) << 4);
  wn[c * 64 + (byte >> 2)] = p;
}

// ---- target-column cosine (for one-hot correction) ----
__global__ void __launch_bounds__(256) k_tdot(const uint32_t* __restrict__ xn,
                                              const uint32_t* __restrict__ wn,
                                              const int* __restrict__ tgt,
                                              float* __restrict__ cost) {
  const int wv = threadIdx.x >> 6, lane = threadIdx.x & 63;
  const int b = blockIdx.x * 4 + wv;                    // 512 blocks
  const int t = tgt[b];
  const uint32_t xa = xn[b * 64 + lane];
  const uint32_t bo = ((uint32_t)(4 * lane)) ^ (((uint32_t)t & 7u) << 4);
  const uint32_t wa = wn[t * 64 + (bo >> 2)];
  float d = bf2f(xa & 0xffffu) * bf2f(wa & 0xffffu) + bf2f(xa >> 16) * bf2f(wa >> 16);
  #pragma unroll
  for (int off = 1; off < 64; off <<= 1) d += __shfl_xor(d, off, 64);
  if (lane == 0) cost[b] = d;
}

// ---- main fused GEMM + margin-transform + exp accumulate ----
// grid = 16 * 125 = 2000 blocks, 256 threads (4 waves, 32 rows each)
// BC=80 -> LDS 2x20KB=40KB -> 4 blocks/CU (16 waves/CU)
__global__ void __launch_bounds__(256, 4) k_main(const uint32_t* __restrict__ xn,
                                                 const uint32_t* __restrict__ wn,
                                                 float* __restrict__ rowsum) {
  __shared__ uint32_t lds[2][BC * 64];                  // 2 x 20 KB
  const int wv = threadIdx.x >> 6, lane = threadIdx.x & 63;
  const int rb = blockIdx.x & 15;                       // row block
  const int cg = blockIdx.x >> 4;                       // class group (125)
  const int rowbase = rb * BR + wv * 32;

  // A fragments: full K=128 in registers (layout: row=lane&15, k=32kk+8q+e)
  bf16x8 afrag[2][4];
  #pragma unroll
  for (int m = 0; m < 2; ++m)
    #pragma unroll
    for (int kk = 0; kk < 4; ++kk) {
      const int row = rowbase + 16 * m + (lane & 15);
      afrag[m][kk] = *reinterpret_cast<const bf16x8*>(xn + row * 64 + 16 * kk + 4 * (lane >> 4));
    }

  auto stage = [&](int tile, int buf) {
    const int cbase = cg * (BC * TPG) + tile * BC;
    const uint32_t* src = wn + (size_t)cbase * 64 + threadIdx.x * 4;
    uint32_t* dst = &lds[buf][threadIdx.x * 4];
    #pragma unroll
    for (int i = 0; i < 5; ++i) {
      __builtin_amdgcn_global_load_lds(
          (const __attribute__((address_space(1))) uint32_t*)(const void*)(src + i * 1024),
          (__attribute__((address_space(3))) uint32_t*)(void*)(dst + i * 1024),
          16, 0, 0);
    }
  };

  float rsum[2][4] = {{0.f,0.f,0.f,0.f},{0.f,0.f,0.f,0.f}};

  stage(0, 0);
  __syncthreads();

  for (int t = 0; t < TPG; ++t) {
    const int cur = t & 1;
    if (t + 1 < TPG) stage(t + 1, cur ^ 1);
    const uint32_t* lb = lds[cur];
    f32x4 acc[2][5] = {};
    #pragma unroll
    for (int kk = 0; kk < 4; ++kk) {
      // per-lane swizzled column offset (dwords): (16kk+4q) ^ ((lane&7)<<2)
      const uint32_t colo = ((uint32_t)(16 * kk + 4 * (lane >> 4))) ^ (((uint32_t)lane & 7u) << 2);
      const uint32_t base = ((uint32_t)(lane & 15)) * 64u + colo;
      bf16x8 bfrag[5];
      #pragma unroll
      for (int n = 0; n < 5; ++n)
        bfrag[n] = *reinterpret_cast<const bf16x8*>(lb + base + 1024u * n);
      #pragma unroll
      for (int m = 0; m < 2; ++m)
        #pragma unroll
        for (int n = 0; n < 5; ++n)
          acc[m][n] = __builtin_amdgcn_mfma_f32_16x16x32_bf16(afrag[m][kk], bfrag[n], acc[m][n], 0, 0, 0);
    }
    // epilogue (R1-proven scalar math): exp2(c*CA - sqrt(1-c^2)*CB + CC)
    #pragma unroll
    for (int m = 0; m < 2; ++m)
      #pragma unroll
      for (int n = 0; n < 5; ++n)
        #pragma unroll
        for (int e = 0; e < 4; ++e) {
          const float c = acc[m][n][e];
          const float s2 = fmaxf(fmaf(-c, c, 1.0f), 0.0f);
          const float sn = __builtin_amdgcn_sqrtf(s2);
          float tt = fmaf(c, CA, CC);
          tt = fmaf(sn, -CB, tt);
          rsum[m][e] += __builtin_amdgcn_exp2f(tt);
        }
    __syncthreads();   // drains vmcnt -> next tile staged; readers done before overwrite
  }

  // reduce over the 16 column-lanes, then one atomic per row
  #pragma unroll
  for (int m = 0; m < 2; ++m)
    #pragma unroll
    for (int e = 0; e < 4; ++e) {
      float v = rsum[m][e];
      #pragma unroll
      for (int off = 1; off < 16; off <<= 1) v += __shfl_xor(v, off, 64);
      if ((lane & 15) == 0)
        atomicAdd(&rowsum[rowbase + 16 * m + 4 * (lane >> 4) + e], v);
    }
}

// ---- finalize: target-term swap, log, mean (R1 version) ----
__global__ void __launch_bounds__(256) k_final(const float* __restrict__ rowsum,
                                               const float* __restrict__ cost,
                                               float* __restrict__ out) {
  __shared__ float red[256];
  float part = 0.f;
  for (int b = threadIdx.x; b < NB; b += 256) {
    const float ct = cost[b];
    const float s2 = fmaxf(fmaf(-ct, ct, 1.0f), 0.0f);
    const float sn = __builtin_amdgcn_sqrtf(s2);
    float tt = fmaf(ct, CA, CC);
    tt = fmaf(sn, -CB, tt);
    const float v_ctm = __builtin_amdgcn_exp2f(tt);           // term main kernel added
    const float logit_t = SCALE * (ct - MM);                  // true target logit
    const float v_tgt = __builtin_amdgcn_exp2f((logit_t - SCALE) * LOG2E);
    float sum = rowsum[b] - v_ctm + v_tgt;
    sum = fmaxf(sum, 1e-37f);
    part += __builtin_amdgcn_logf(sum) * 0.6931471805599453f + SCALE - logit_t;
  }
  red[threadIdx.x] = part;
  __syncthreads();
  #pragma unroll
  for (int s = 128; s > 0; s >>= 1) {
    if (threadIdx.x < s) red[threadIdx.x] += red[threadIdx.x + s];
    __syncthreads();
  }
  if (threadIdx.x == 0) out[0] = red[0] * (1.0f / NB);
}

extern "C" void kernel_launch(void* const* d_in, const int* in_sizes, int n_in,
                              void* d_out, int out_size, void* d_ws, size_t ws_size,
                              hipStream_t stream) {
  const float* x   = (const float*)d_in[0];
  const int*   tgt = (const int*)d_in[1];
  const float* w   = (const float*)d_in[2];
  float* out = (float*)d_out;

  char* ws = (char*)d_ws;
  const size_t WN_B = (size_t)NC * 256;        // 25,600,000
  const size_t XN_B = (size_t)NB * 256;        // 524,288
  uint32_t* wn     = (uint32_t*)ws;
  uint32_t* xn     = (uint32_t*)(ws + WN_B);
  float*    cost   = (float*)(ws + WN_B + XN_B);
  float*    rowsum = (float*)(ws + WN_B + XN_B + NB * 4);
  if (ws_size < WN_B + XN_B + (size_t)NB * 8) return;

  k_norm_x<<<512,   256, 0, stream>>>(x, xn, rowsum);
  k_norm_w<<<25000, 256, 0, stream>>>(w, wn);
  k_tdot <<<512,   256, 0, stream>>>(xn, wn, tgt, cost);
  k_main <<<2000,  256, 0, stream>>>(xn, wn, rowsum);
  k_final<<<1,     256, 0, stream>>>(rowsum, cost, out);
}

// Round 4
// 96.169 us; speedup vs baseline: 1.1784x; 1.1403x over previous
//
#include <hip/hip_runtime.h>
#include <stdint.h>

typedef __bf16 bf16x8 __attribute__((ext_vector_type(8)));
typedef float  f32x4  __attribute__((ext_vector_type(4)));

// ArcFace constants (margin=0.5, scale=70)
constexpr float COS_M = 0.8775825618903728f;
constexpr float SIN_M = 0.4794255386042030f;
constexpr float MM    = 0.2397127693021015f;   // sin(pi-0.5)*0.5
constexpr float SCALE = 70.0f;
constexpr float LOG2E = 1.4426950408889634f;
constexpr float CA =  SCALE * COS_M * LOG2E;   // coeff on cos
constexpr float CB =  SCALE * SIN_M * LOG2E;   // coeff on sin
constexpr float CC = -SCALE * LOG2E;           // -70 shift, log2 domain

// skip threshold: c < 0.21 -> tt < -129.7 (log2); row sums ~2^-105, tail mass
// < 2^-121 -> relative error ~1e-5, threshold is 0.2. Wave-uniform skip.
constexpr float C0 = 0.21f;

constexpr int NB = 2048, NC = 100000, ND = 128;
constexpr int BR = 128, BC = 80, TPG = 10;     // grid = 16 row-blocks x 125 class-groups

__device__ __forceinline__ unsigned short f2bf(float f) {
  union { float f; uint32_t u; } x; x.f = f;
  uint32_t u = x.u;
  return (unsigned short)((u + 0x7fffu + ((u >> 16) & 1u)) >> 16);  // RNE
}
__device__ __forceinline__ float bf2f(uint32_t bits16) {
  union { uint32_t u; float f; } x; x.u = bits16 << 16;
  return x.f;
}

// ---- normalize x rows -> bf16 (linear layout); also zero rowsum ----
__global__ void __launch_bounds__(256) k_norm_x(const float* __restrict__ x,
                                                uint32_t* __restrict__ xn,
                                                float* __restrict__ rowsum) {
  const int wv = threadIdx.x >> 6, lane = threadIdx.x & 63;
  if (blockIdx.x < 8) rowsum[blockIdx.x * 256 + threadIdx.x] = 0.0f;
  const int row = blockIdx.x * 4 + wv;                  // 512 blocks
  const float2 v = reinterpret_cast<const float2*>(x + row * ND)[lane];
  float ss = v.x * v.x + v.y * v.y;
  #pragma unroll
  for (int off = 1; off < 64; off <<= 1) ss += __shfl_xor(ss, off, 64);
  const float sc = __builtin_amdgcn_rsqf(fmaxf(ss, 1e-24f));
  const uint32_t p = (uint32_t)f2bf(v.x * sc) | ((uint32_t)f2bf(v.y * sc) << 16);
  xn[row * 64 + lane] = p;
}

// ---- normalize weight rows -> bf16, stored XOR-swizzled (byte ^= (c&7)<<4) ----
__global__ void __launch_bounds__(256) k_norm_w(const float* __restrict__ w,
                                                uint32_t* __restrict__ wn) {
  const int wv = threadIdx.x >> 6, lane = threadIdx.x & 63;
  const int c = blockIdx.x * 4 + wv;                    // 25000 blocks
  const float2 v = reinterpret_cast<const float2*>(w + c * ND)[lane];
  float ss = v.x * v.x + v.y * v.y;
  #pragma unroll
  for (int off = 1; off < 64; off <<= 1) ss += __shfl_xor(ss, off, 64);
  const float sc = __builtin_amdgcn_rsqf(fmaxf(ss, 1e-24f));
  const uint32_t p = (uint32_t)f2bf(v.x * sc) | ((uint32_t)f2bf(v.y * sc) << 16);
  const uint32_t byte = ((uint32_t)(4 * lane)) ^ (((uint32_t)c & 7u) << 4);
  wn[c * 64 + (byte >> 2)] = p;
}

// ---- target-column cosine (for one-hot correction) ----
__global__ void __launch_bounds__(256) k_tdot(const uint32_t* __restrict__ xn,
                                              const uint32_t* __restrict__ wn,
                                              const int* __restrict__ tgt,
                                              float* __restrict__ cost) {
  const int wv = threadIdx.x >> 6, lane = threadIdx.x & 63;
  const int b = blockIdx.x * 4 + wv;                    // 512 blocks
  const int t = tgt[b];
  const uint32_t xa = xn[b * 64 + lane];
  const uint32_t bo = ((uint32_t)(4 * lane)) ^ (((uint32_t)t & 7u) << 4);
  const uint32_t wa = wn[t * 64 + (bo >> 2)];
  float d = bf2f(xa & 0xffffu) * bf2f(wa & 0xffffu) + bf2f(xa >> 16) * bf2f(wa >> 16);
  #pragma unroll
  for (int off = 1; off < 64; off <<= 1) d += __shfl_xor(d, off, 64);
  if (lane == 0) cost[b] = d;
}

// ---- main fused GEMM + margin-transform + exp accumulate ----
// grid = 16 * 125 = 2000 blocks, 256 threads (4 waves, 32 rows each)
// BC=80 -> LDS 2x20KB=40KB -> 4 blocks/CU (16 waves/CU)
__global__ void __launch_bounds__(256, 4) k_main(const uint32_t* __restrict__ xn,
                                                 const uint32_t* __restrict__ wn,
                                                 float* __restrict__ rowsum) {
  __shared__ uint32_t lds[2][BC * 64];                  // 2 x 20 KB
  const int wv = threadIdx.x >> 6, lane = threadIdx.x & 63;
  const int rb = blockIdx.x & 15;                       // row block
  const int cg = blockIdx.x >> 4;                       // class group (125)
  const int rowbase = rb * BR + wv * 32;

  // A fragments: full K=128 in registers (layout: row=lane&15, k=32kk+8q+e)
  bf16x8 afrag[2][4];
  #pragma unroll
  for (int m = 0; m < 2; ++m)
    #pragma unroll
    for (int kk = 0; kk < 4; ++kk) {
      const int row = rowbase + 16 * m + (lane & 15);
      afrag[m][kk] = *reinterpret_cast<const bf16x8*>(xn + row * 64 + 16 * kk + 4 * (lane >> 4));
    }

  auto stage = [&](int tile, int buf) {
    const int cbase = cg * (BC * TPG) + tile * BC;
    const uint32_t* src = wn + (size_t)cbase * 64 + threadIdx.x * 4;
    uint32_t* dst = &lds[buf][threadIdx.x * 4];
    #pragma unroll
    for (int i = 0; i < 5; ++i) {
      __builtin_amdgcn_global_load_lds(
          (const __attribute__((address_space(1))) uint32_t*)(const void*)(src + i * 1024),
          (__attribute__((address_space(3))) uint32_t*)(void*)(dst + i * 1024),
          16, 0, 0);
    }
  };

  float rsum[2][4] = {{0.f,0.f,0.f,0.f},{0.f,0.f,0.f,0.f}};

  stage(0, 0);
  __syncthreads();

  for (int t = 0; t < TPG; ++t) {
    const int cur = t & 1;
    if (t + 1 < TPG) stage(t + 1, cur ^ 1);
    const uint32_t* lb = lds[cur];
    f32x4 acc[2][5] = {};
    #pragma unroll
    for (int kk = 0; kk < 4; ++kk) {
      // per-lane swizzled column offset (dwords): (16kk+4q) ^ ((lane&7)<<2)
      const uint32_t colo = ((uint32_t)(16 * kk + 4 * (lane >> 4))) ^ (((uint32_t)lane & 7u) << 2);
      const uint32_t base = ((uint32_t)(lane & 15)) * 64u + colo;
      bf16x8 bfrag[5];
      #pragma unroll
      for (int n = 0; n < 5; ++n)
        bfrag[n] = *reinterpret_cast<const bf16x8*>(lb + base + 1024u * n);
      #pragma unroll
      for (int m = 0; m < 2; ++m)
        #pragma unroll
        for (int n = 0; n < 5; ++n)
          acc[m][n] = __builtin_amdgcn_mfma_f32_16x16x32_bf16(afrag[m][kk], bfrag[n], acc[m][n], 0, 0, 0);
    }
    // epilogue: exp2(c*CA - sqrt(1-c^2)*CB + CC), with wave-uniform skip of
    // groups whose 64 values are all below the contribution threshold
    #pragma unroll
    for (int m = 0; m < 2; ++m)
      #pragma unroll
      for (int n = 0; n < 5; ++n)
        #pragma unroll
        for (int e = 0; e < 4; ++e) {
          const float c = acc[m][n][e];
          if (__any(c > C0)) {
            const float s2 = fmaxf(fmaf(-c, c, 1.0f), 0.0f);
            const float sn = __builtin_amdgcn_sqrtf(s2);
            float tt = fmaf(c, CA, CC);
            tt = fmaf(sn, -CB, tt);
            rsum[m][e] += __builtin_amdgcn_exp2f(tt);
          }
        }
    __syncthreads();   // drains vmcnt -> next tile staged; readers done before overwrite
  }

  // reduce over the 16 column-lanes, then one atomic per row
  #pragma unroll
  for (int m = 0; m < 2; ++m)
    #pragma unroll
    for (int e = 0; e < 4; ++e) {
      float v = rsum[m][e];
      #pragma unroll
      for (int off = 1; off < 16; off <<= 1) v += __shfl_xor(v, off, 64);
      if ((lane & 15) == 0)
        atomicAdd(&rowsum[rowbase + 16 * m + 4 * (lane >> 4) + e], v);
    }
}

// ---- finalize: target-term swap, log, mean ----
__global__ void __launch_bounds__(256) k_final(const float* __restrict__ rowsum,
                                               const float* __restrict__ cost,
                                               float* __restrict__ out) {
  __shared__ float red[256];
  float part = 0.f;
  for (int b = threadIdx.x; b < NB; b += 256) {
    const float ct = cost[b];
    const float s2 = fmaxf(fmaf(-ct, ct, 1.0f), 0.0f);
    const float sn = __builtin_amdgcn_sqrtf(s2);
    float tt = fmaf(ct, CA, CC);
    tt = fmaf(sn, -CB, tt);
    const float v_ctm = (ct > C0) ? __builtin_amdgcn_exp2f(tt) : 0.0f;  // what k_main added (0 if its wave-group could have skipped: value underflows anyway)
    const float logit_t = SCALE * (ct - MM);                  // true target logit
    const float v_tgt = __builtin_amdgcn_exp2f((logit_t - SCALE) * LOG2E);
    float sum = rowsum[b] - v_ctm + v_tgt;
    sum = fmaxf(sum, 1e-37f);
    part += __builtin_amdgcn_logf(sum) * 0.6931471805599453f + SCALE - logit_t;
  }
  red[threadIdx.x] = part;
  __syncthreads();
  #pragma unroll
  for (int s = 128; s > 0; s >>= 1) {
    if (threadIdx.x < s) red[threadIdx.x] += red[threadIdx.x + s];
    __syncthreads();
  }
  if (threadIdx.x == 0) out[0] = red[0] * (1.0f / NB);
}

extern "C" void kernel_launch(void* const* d_in, const int* in_sizes, int n_in,
                              void* d_out, int out_size, void* d_ws, size_t ws_size,
                              hipStream_t stream) {
  const float* x   = (const float*)d_in[0];
  const int*   tgt = (const int*)d_in[1];
  const float* w   = (const float*)d_in[2];
  float* out = (float*)d_out;

  char* ws = (char*)d_ws;
  const size_t WN_B = (size_t)NC * 256;        // 25,600,000
  const size_t XN_B = (size_t)NB * 256;        // 524,288
  uint32_t* wn     = (uint32_t*)ws;
  uint32_t* xn     = (uint32_t*)(ws + WN_B);
  float*    cost   = (float*)(ws + WN_B + XN_B);
  float*    rowsum = (float*)(ws + WN_B + XN_B + NB * 4);
  if (ws_size < WN_B + XN_B + (size_t)NB * 8) return;

  k_norm_x<<<512,   256, 0, stream>>>(x, xn, rowsum);
  k_norm_w<<<25000, 256, 0, stream>>>(w, wn);
  k_tdot <<<512,   256, 0, stream>>>(xn, wn, tgt, cost);
  k_main <<<2000,  256, 0, stream>>>(xn, wn, rowsum);
  k_final<<<1,     256, 0, stream>>>(rowsum, cost, out);
}